// Round 14
// baseline (87.905 us; speedup 1.0000x reference)
//
#include <hip/hip_runtime.h>
#include <hip/hip_bf16.h>

#define LNUM 13
#define FDIM 768
#define SDIM 512
#define BNUM 32
#define H1DIM 512
#define H2DIM 256
#define GA0 496            // target blocks for apportionment
#define GPAD (GA0 + 16)    // 512 launched blocks = 2 blocks/CU (12 waves/CU)

typedef float f32x4 __attribute__((ext_vector_type(4)));  // native vec for nt-load

// Deterministic apportionment: n_b = ceil(len_b * GA0 / T), BB = prefix(n_b).
// Computed identically (integer math) in kA and kStatsFC1.

// ---------------- Kernel A (R13-identical): block g handles a contiguous s-range
// of batch b; 384 thr = 2 s-groups of 192; halves combined in LDS, slot g written.
// x loads are non-temporal (read-once; cache allocation at 654MB scale is overhead).
__global__ __launch_bounds__(384) void kA_partials(
    const float* __restrict__ x, const int* __restrict__ lengths,
    const float* __restrict__ lw, float* __restrict__ partial) {
  __shared__ int lenS[BNUM];
  __shared__ int BB[BNUM + 1];
  __shared__ float wS[LNUM];
  __shared__ float comb[2 * FDIM];     // half-1 sum[768] + sq[768]
  const int tid = threadIdx.x;
  const int h  = tid / 192;            // s-subgroup 0/1
  const int tl = tid % 192;            // covers f = 4*tl .. 4*tl+3

  if (tid < BNUM) lenS[tid] = lengths[tid];
  __syncthreads();
  if (tid == 0) {
    int T = 0;
    #pragma unroll
    for (int b = 0; b < BNUM; ++b) T += lenS[b];
    int acc = 0; BB[0] = 0;
    #pragma unroll
    for (int b = 0; b < BNUM; ++b) {
      int nb = (T > 0 && lenS[b] > 0) ? (lenS[b] * GA0 + T - 1) / T : 0;
      acc += nb; BB[b + 1] = acc;
    }
    float m = lw[0];
    #pragma unroll
    for (int l = 1; l < LNUM; ++l) m = fmaxf(m, lw[l]);
    float e[LNUM]; float s = 0.f;
    #pragma unroll
    for (int l = 0; l < LNUM; ++l) { e[l] = expf(lw[l] - m); s += e[l]; }
    #pragma unroll
    for (int l = 0; l < LNUM; ++l) wS[l] = e[l] / s;
  }
  __syncthreads();

  const int g = blockIdx.x;
  if (g >= BB[BNUM]) return;           // idle block; its slot is never read

  int lo = 0, hi = BNUM;
  while (hi - lo > 1) { int mid = (lo + hi) >> 1; if (g >= BB[mid]) lo = mid; else hi = mid; }
  const int b   = lo;
  const int i   = g - BB[b];
  const int n   = BB[b + 1] - BB[b];
  const int len = lenS[b];
  const int base = len / n, rem = len % n;
  const int s0 = i * base + min(i, rem);
  const int cnt = base + (i < rem ? 1 : 0);

  float4 sum = make_float4(0.f, 0.f, 0.f, 0.f);
  float4 sq  = make_float4(0.f, 0.f, 0.f, 0.f);
  const float* xb = x + (size_t)b * SDIM * (LNUM * FDIM) + (size_t)tl * 4;

  for (int s = s0 + h; s < s0 + cnt; s += 2) {
    const float* xs = xb + (size_t)s * (LNUM * FDIM);
    float4 word = make_float4(0.f, 0.f, 0.f, 0.f);
    #pragma unroll
    for (int l = 0; l < LNUM; ++l) {
      f32x4 v = __builtin_nontemporal_load(
          reinterpret_cast<const f32x4*>(xs + l * FDIM));
      const float wl = wS[l];
      word.x = fmaf(wl, v.x, word.x);
      word.y = fmaf(wl, v.y, word.y);
      word.z = fmaf(wl, v.z, word.z);
      word.w = fmaf(wl, v.w, word.w);
    }
    sum.x += word.x; sum.y += word.y; sum.z += word.z; sum.w += word.w;
    sq.x = fmaf(word.x, word.x, sq.x);
    sq.y = fmaf(word.y, word.y, sq.y);
    sq.z = fmaf(word.z, word.z, sq.z);
    sq.w = fmaf(word.w, word.w, sq.w);
  }

  // combine halves (fixed order: half0 += half1) and write slot g
  if (h == 1) {
    *reinterpret_cast<float4*>(&comb[4 * tl]) = sum;
    *reinterpret_cast<float4*>(&comb[FDIM + 4 * tl]) = sq;
  }
  __syncthreads();
  if (h == 0) {
    float4 s1 = *reinterpret_cast<const float4*>(&comb[4 * tl]);
    float4 q1 = *reinterpret_cast<const float4*>(&comb[FDIM + 4 * tl]);
    sum.x += s1.x; sum.y += s1.y; sum.z += s1.z; sum.w += s1.w;
    sq.x  += q1.x; sq.y  += q1.y; sq.z  += q1.z; sq.w  += q1.w;
    float* p = partial + (size_t)g * (2 * FDIM) + (size_t)tl * 4;
    *reinterpret_cast<float4*>(p) = sum;        // zeros if cnt==0 (slot is read)
    *reinterpret_cast<float4*>(p + FDIM) = sq;
  }
}

// ---------------- Kernel SC: fused stats + FC1. grid = B*4 (j-tiles of 128), 512 thr.
// Each block reduces its b's slot range into feats-in-LDS (4x redundant partial
// reads, L2/L3-resident), then h1 j-tile = relu(feats @ W1 + b1).
__global__ __launch_bounds__(512) void kStatsFC1(
    const float* __restrict__ partial, const int* __restrict__ lengths,
    const float* __restrict__ W1, const float* __restrict__ b1,
    float* __restrict__ h1) {
  const int b  = blockIdx.x >> 2;
  const int jt = blockIdx.x & 3;
  const int t  = threadIdx.x;

  __shared__ int lenS[BNUM];
  __shared__ int BB[BNUM + 1];
  __shared__ float fs[2 * FDIM];      // 6 KB: mean[768] | sd[768]
  __shared__ float red[4][128];       // 2 KB

  if (t < BNUM) lenS[t] = lengths[t];
  __syncthreads();
  if (t == 0) {
    int T = 0;
    #pragma unroll
    for (int bb = 0; bb < BNUM; ++bb) T += lenS[bb];
    int acc = 0; BB[0] = 0;
    #pragma unroll
    for (int bb = 0; bb < BNUM; ++bb) {
      int nb = (T > 0 && lenS[bb] > 0) ? (lenS[bb] * GA0 + T - 1) / T : 0;
      acc += nb; BB[bb + 1] = acc;
    }
  }
  __syncthreads();

  const int cBeg = BB[b], cEnd = BB[b + 1];
  const int n = lenS[b];
  const float fn = (float)n;
  const float inv_n  = 1.f / fmaxf(fn, 1.f);
  const float inv_n1 = 1.f / fmaxf(fn - 1.f, 1.f);

  for (int f = t; f < FDIM; f += 512) {
    float ms = 0.f, mq = 0.f;
    for (int cc = cBeg; cc < cEnd; ++cc) {
      const float* p = partial + (size_t)cc * (2 * FDIM);
      ms += p[f];
      mq += p[FDIM + f];
    }
    const float mean = ms * inv_n;
    const float var = (mq - fn * mean * mean) * inv_n1;
    fs[f]        = mean;
    fs[FDIM + f] = (n > 1) ? sqrtf(fmaxf(var, 0.f)) : 0.f;
  }
  __syncthreads();

  // FC1 j-tile (identical structure to R7 kFC1)
  const int jl = t & 127;
  const int kh = t >> 7;              // 0..3
  const int j  = jt * 128 + jl;
  const float* wcol = W1 + (size_t)kh * 384 * H1DIM + j;
  const float* fk = fs + kh * 384;
  float acc = 0.f;
  #pragma unroll 16
  for (int i = 0; i < 384; ++i)
    acc = fmaf(fk[i], wcol[(size_t)i * H1DIM], acc);
  red[kh][jl] = acc;
  __syncthreads();

  if (t < 128) {
    float a = red[0][t] + red[1][t] + red[2][t] + red[3][t] + b1[jt * 128 + t];
    h1[(size_t)b * H1DIM + jt * 128 + t] = fmaxf(a, 0.f);
  }
}

// ---------------- Kernel D: h2 = relu(h1 @ W2 + b2); out = h2 @ W3 + b3  (R7-identical)
__global__ __launch_bounds__(512) void kFC23(
    const float* __restrict__ h1, const float* __restrict__ W2,
    const float* __restrict__ b2, const float* __restrict__ W3,
    const float* __restrict__ b3, float* __restrict__ out) {
  const int b = blockIdx.x;
  const int t = threadIdx.x;
  const int jl = t & 255;
  const int kh = t >> 8;              // 0..1

  __shared__ float hs[H1DIM];         // 2 KB
  __shared__ float red[2 * H2DIM];    // 2 KB
  __shared__ float wred[8];

  if (t < H1DIM) hs[t] = h1[(size_t)b * H1DIM + t];
  __syncthreads();

  const float* wcol = W2 + (size_t)kh * 256 * H2DIM + jl;
  const float* hk = hs + kh * 256;
  float acc = 0.f;
  #pragma unroll 16
  for (int i = 0; i < 256; ++i)
    acc = fmaf(hk[i], wcol[(size_t)i * H2DIM], acc);
  red[kh * H2DIM + jl] = acc;
  __syncthreads();

  float v = 0.f;
  if (t < H2DIM) {
    const float h2 = fmaxf(red[t] + red[H2DIM + t] + b2[t], 0.f);
    v = h2 * W3[t];
  }
  #pragma unroll
  for (int off = 32; off > 0; off >>= 1) v += __shfl_down(v, off, 64);
  if ((t & 63) == 0) wred[t >> 6] = v;
  __syncthreads();
  if (t == 0) {
    float r = b3[0];
    #pragma unroll
    for (int i = 0; i < 8; ++i) r += wred[i];
    out[b] = r;
  }
}

extern "C" void kernel_launch(void* const* d_in, const int* in_sizes, int n_in,
                              void* d_out, int out_size, void* d_ws, size_t ws_size,
                              hipStream_t stream) {
  const float* x       = (const float*)d_in[0];
  const int*   lengths = (const int*)  d_in[1];
  const float* lw      = (const float*)d_in[2];
  const float* W1      = (const float*)d_in[3];
  const float* b1      = (const float*)d_in[4];
  const float* W2      = (const float*)d_in[5];
  const float* b2      = (const float*)d_in[6];
  const float* W3      = (const float*)d_in[7];
  const float* b3      = (const float*)d_in[8];
  float* out = (float*)d_out;

  float* partial = (float*)d_ws;                              // GPAD * 2F floats (3.1 MB)
  float* h1      = partial + (size_t)GPAD * 2 * FDIM;         // B * H1

  kA_partials<<<dim3(GPAD), dim3(384), 0, stream>>>(x, lengths, lw, partial);
  kStatsFC1<<<dim3(BNUM * 4), dim3(512), 0, stream>>>(partial, lengths, W1, b1, h1);
  kFC23<<<dim3(BNUM), dim3(512), 0, stream>>>(h1, W2, b2, W3, b3, out);
}

// Round 15
// 76.775 us; speedup vs baseline: 1.1450x; 1.1450x over previous
//
#include <hip/hip_runtime.h>
#include <hip/hip_bf16.h>

#define LNUM 13
#define FDIM 768
#define SDIM 512
#define BNUM 32
#define H1DIM 512
#define H2DIM 256
#define GA0 496            // target blocks for apportionment
#define GPAD (GA0 + 16)    // 512 launched blocks = 2 blocks/CU (12 waves/CU)

typedef float f32x4 __attribute__((ext_vector_type(4)));  // native vec for nt-load

// Deterministic apportionment: n_b = ceil(len_b * GA0 / T), BB = prefix(n_b).
// Computed identically (integer math) in kA and kStats.

// ---------------- Kernel A (R13-identical): block g handles a contiguous s-range
// of batch b; 384 thr = 2 s-groups of 192; halves combined in LDS, slot g written.
// x loads are non-temporal (read-once; cache allocation at 654MB scale is overhead).
__global__ __launch_bounds__(384) void kA_partials(
    const float* __restrict__ x, const int* __restrict__ lengths,
    const float* __restrict__ lw, float* __restrict__ partial) {
  __shared__ int lenS[BNUM];
  __shared__ int BB[BNUM + 1];
  __shared__ float wS[LNUM];
  __shared__ float comb[2 * FDIM];     // half-1 sum[768] + sq[768]
  const int tid = threadIdx.x;
  const int h  = tid / 192;            // s-subgroup 0/1
  const int tl = tid % 192;            // covers f = 4*tl .. 4*tl+3

  if (tid < BNUM) lenS[tid] = lengths[tid];
  __syncthreads();
  if (tid == 0) {
    int T = 0;
    #pragma unroll
    for (int b = 0; b < BNUM; ++b) T += lenS[b];
    int acc = 0; BB[0] = 0;
    #pragma unroll
    for (int b = 0; b < BNUM; ++b) {
      int nb = (T > 0 && lenS[b] > 0) ? (lenS[b] * GA0 + T - 1) / T : 0;
      acc += nb; BB[b + 1] = acc;
    }
    float m = lw[0];
    #pragma unroll
    for (int l = 1; l < LNUM; ++l) m = fmaxf(m, lw[l]);
    float e[LNUM]; float s = 0.f;
    #pragma unroll
    for (int l = 0; l < LNUM; ++l) { e[l] = expf(lw[l] - m); s += e[l]; }
    #pragma unroll
    for (int l = 0; l < LNUM; ++l) wS[l] = e[l] / s;
  }
  __syncthreads();

  const int g = blockIdx.x;
  if (g >= BB[BNUM]) return;           // idle block; its slot is never read

  int lo = 0, hi = BNUM;
  while (hi - lo > 1) { int mid = (lo + hi) >> 1; if (g >= BB[mid]) lo = mid; else hi = mid; }
  const int b   = lo;
  const int i   = g - BB[b];
  const int n   = BB[b + 1] - BB[b];
  const int len = lenS[b];
  const int base = len / n, rem = len % n;
  const int s0 = i * base + min(i, rem);
  const int cnt = base + (i < rem ? 1 : 0);

  float4 sum = make_float4(0.f, 0.f, 0.f, 0.f);
  float4 sq  = make_float4(0.f, 0.f, 0.f, 0.f);
  const float* xb = x + (size_t)b * SDIM * (LNUM * FDIM) + (size_t)tl * 4;

  for (int s = s0 + h; s < s0 + cnt; s += 2) {
    const float* xs = xb + (size_t)s * (LNUM * FDIM);
    float4 word = make_float4(0.f, 0.f, 0.f, 0.f);
    #pragma unroll
    for (int l = 0; l < LNUM; ++l) {
      f32x4 v = __builtin_nontemporal_load(
          reinterpret_cast<const f32x4*>(xs + l * FDIM));
      const float wl = wS[l];
      word.x = fmaf(wl, v.x, word.x);
      word.y = fmaf(wl, v.y, word.y);
      word.z = fmaf(wl, v.z, word.z);
      word.w = fmaf(wl, v.w, word.w);
    }
    sum.x += word.x; sum.y += word.y; sum.z += word.z; sum.w += word.w;
    sq.x = fmaf(word.x, word.x, sq.x);
    sq.y = fmaf(word.y, word.y, sq.y);
    sq.z = fmaf(word.z, word.z, sq.z);
    sq.w = fmaf(word.w, word.w, sq.w);
  }

  // combine halves (fixed order: half0 += half1) and write slot g
  if (h == 1) {
    *reinterpret_cast<float4*>(&comb[4 * tl]) = sum;
    *reinterpret_cast<float4*>(&comb[FDIM + 4 * tl]) = sq;
  }
  __syncthreads();
  if (h == 0) {
    float4 s1 = *reinterpret_cast<const float4*>(&comb[4 * tl]);
    float4 q1 = *reinterpret_cast<const float4*>(&comb[FDIM + 4 * tl]);
    sum.x += s1.x; sum.y += s1.y; sum.z += s1.z; sum.w += s1.w;
    sq.x  += q1.x; sq.y  += q1.y; sq.z  += q1.z; sq.w  += q1.w;
    float* p = partial + (size_t)g * (2 * FDIM) + (size_t)tl * 4;
    *reinterpret_cast<float4*>(p) = sum;        // zeros if cnt==0 (slot is read)
    *reinterpret_cast<float4*>(p + FDIM) = sq;
  }
}

// ---------------- Kernel S (R13-identical): reduce slots [BB[b], BB[b+1]) -> feats
__global__ __launch_bounds__(256) void kStats(
    const float* __restrict__ partial, const int* __restrict__ lengths,
    float* __restrict__ feats) {
  const int b  = blockIdx.x / 12;
  const int cg = blockIdx.x % 12;
  const int cl = threadIdx.x & 63;
  const int k  = threadIdx.x >> 6;      // 0..3
  const int f  = cg * 64 + cl;

  __shared__ int lenS[BNUM];
  __shared__ int BB[BNUM + 1];
  if (threadIdx.x < BNUM) lenS[threadIdx.x] = lengths[threadIdx.x];
  __syncthreads();
  if (threadIdx.x == 0) {
    int T = 0;
    #pragma unroll
    for (int bb = 0; bb < BNUM; ++bb) T += lenS[bb];
    int acc = 0; BB[0] = 0;
    #pragma unroll
    for (int bb = 0; bb < BNUM; ++bb) {
      int nb = (T > 0 && lenS[bb] > 0) ? (lenS[bb] * GA0 + T - 1) / T : 0;
      acc += nb; BB[bb + 1] = acc;
    }
  }
  __syncthreads();

  const int cBeg = BB[b], cEnd = BB[b + 1];
  float ms = 0.f, mq = 0.f;
  for (int cc = cBeg + k; cc < cEnd; cc += 4) {
    const float* p = partial + (size_t)cc * (2 * FDIM);
    ms += p[f];
    mq += p[FDIM + f];
  }
  __shared__ float rs[4][64], rq[4][64];
  rs[k][cl] = ms; rq[k][cl] = mq;
  __syncthreads();

  if (threadIdx.x < 64) {
    ms = rs[0][cl] + rs[1][cl] + rs[2][cl] + rs[3][cl];
    mq = rq[0][cl] + rq[1][cl] + rq[2][cl] + rq[3][cl];
    const int n = lenS[b];
    const float fn = (float)n;
    const float mean = ms / fmaxf(fn, 1.f);
    const float var = (mq - fn * mean * mean) / fmaxf(fn - 1.f, 1.f);
    const float sd = (n > 1) ? sqrtf(fmaxf(var, 0.f)) : 0.f;
    feats[(size_t)b * 2 * FDIM + f] = mean;
    feats[(size_t)b * 2 * FDIM + FDIM + f] = sd;
  }
}

// ---------------- Kernel C: h1 = relu(feats @ W1 + b1), batch-blocked x4.
// grid = 8 b-groups x 16 j-tiles(32 cols) = 128 blocks, 512 thr = 32 j x 16 k-slices.
// Each W1 element read once per b-group -> aggregate W1 traffic 24MB (was 96MB).
__global__ __launch_bounds__(512) void kFC1b(
    const float* __restrict__ feats, const float* __restrict__ W1,
    const float* __restrict__ b1, float* __restrict__ h1) {
  const int bg = blockIdx.x >> 4;      // 0..7 (4 consecutive b's)
  const int jt = blockIdx.x & 15;      // 0..15 (32 cols each)
  const int t  = threadIdx.x;
  const int jl = t & 31;
  const int kh = t >> 5;               // 0..15 (96 k's each)
  const int j  = jt * 32 + jl;

  __shared__ float fs[4][2 * FDIM];    // 24 KB
  __shared__ float red[16][4][32];     // 8 KB

  for (int i = t; i < 4 * 2 * FDIM; i += 512) {
    const int bb = i / (2 * FDIM), ff = i % (2 * FDIM);
    fs[bb][ff] = feats[(size_t)(bg * 4 + bb) * 2 * FDIM + ff];
  }
  __syncthreads();

  float a0 = 0.f, a1 = 0.f, a2 = 0.f, a3 = 0.f;
  const float* wp = W1 + (size_t)kh * 96 * H1DIM + j;
  const int k0 = kh * 96;
  #pragma unroll 8
  for (int i = 0; i < 96; ++i) {
    const float w = wp[(size_t)i * H1DIM];
    a0 = fmaf(fs[0][k0 + i], w, a0);
    a1 = fmaf(fs[1][k0 + i], w, a1);
    a2 = fmaf(fs[2][k0 + i], w, a2);
    a3 = fmaf(fs[3][k0 + i], w, a3);
  }
  red[kh][0][jl] = a0;
  red[kh][1][jl] = a1;
  red[kh][2][jl] = a2;
  red[kh][3][jl] = a3;
  __syncthreads();

  if (t < 128) {
    const int bb = t >> 5, jj = t & 31;
    float a = b1[jt * 32 + jj];
    #pragma unroll
    for (int kk = 0; kk < 16; ++kk) a += red[kk][bb][jj];
    h1[(size_t)(bg * 4 + bb) * H1DIM + jt * 32 + jj] = fmaxf(a, 0.f);
  }
}

// ---------------- Kernel D (R13-identical): h2 = relu(h1 @ W2 + b2); out = h2 @ W3 + b3
__global__ __launch_bounds__(512) void kFC23(
    const float* __restrict__ h1, const float* __restrict__ W2,
    const float* __restrict__ b2, const float* __restrict__ W3,
    const float* __restrict__ b3, float* __restrict__ out) {
  const int b = blockIdx.x;
  const int t = threadIdx.x;
  const int jl = t & 255;
  const int kh = t >> 8;              // 0..1

  __shared__ float hs[H1DIM];         // 2 KB
  __shared__ float red[2 * H2DIM];    // 2 KB
  __shared__ float wred[8];

  if (t < H1DIM) hs[t] = h1[(size_t)b * H1DIM + t];
  __syncthreads();

  const float* wcol = W2 + (size_t)kh * 256 * H2DIM + jl;
  const float* hk = hs + kh * 256;
  float acc = 0.f;
  #pragma unroll 16
  for (int i = 0; i < 256; ++i)
    acc = fmaf(hk[i], wcol[(size_t)i * H2DIM], acc);
  red[kh * H2DIM + jl] = acc;
  __syncthreads();

  float v = 0.f;
  if (t < H2DIM) {
    const float h2 = fmaxf(red[t] + red[H2DIM + t] + b2[t], 0.f);
    v = h2 * W3[t];
  }
  #pragma unroll
  for (int off = 32; off > 0; off >>= 1) v += __shfl_down(v, off, 64);
  if ((t & 63) == 0) wred[t >> 6] = v;
  __syncthreads();
  if (t == 0) {
    float r = b3[0];
    #pragma unroll
    for (int i = 0; i < 8; ++i) r += wred[i];
    out[b] = r;
  }
}

extern "C" void kernel_launch(void* const* d_in, const int* in_sizes, int n_in,
                              void* d_out, int out_size, void* d_ws, size_t ws_size,
                              hipStream_t stream) {
  const float* x       = (const float*)d_in[0];
  const int*   lengths = (const int*)  d_in[1];
  const float* lw      = (const float*)d_in[2];
  const float* W1      = (const float*)d_in[3];
  const float* b1      = (const float*)d_in[4];
  const float* W2      = (const float*)d_in[5];
  const float* b2      = (const float*)d_in[6];
  const float* W3      = (const float*)d_in[7];
  const float* b3      = (const float*)d_in[8];
  float* out = (float*)d_out;

  float* partial = (float*)d_ws;                              // GPAD * 2F floats (3.1 MB)
  float* feats   = partial + (size_t)GPAD * 2 * FDIM;         // B * 2F
  float* h1      = feats + (size_t)BNUM * 2 * FDIM;           // B * H1

  kA_partials<<<dim3(GPAD), dim3(384), 0, stream>>>(x, lengths, lw, partial);
  kStats<<<dim3(BNUM * 12), dim3(256), 0, stream>>>(partial, lengths, feats);
  kFC1b<<<dim3(128), dim3(512), 0, stream>>>(feats, W1, b1, h1);
  kFC23<<<dim3(BNUM), dim3(512), 0, stream>>>(h1, W2, b2, W3, b3, out);
}

// Round 17
// 74.264 us; speedup vs baseline: 1.1837x; 1.0338x over previous
//
#include <hip/hip_runtime.h>
#include <hip/hip_bf16.h>

#define LNUM 13
#define FDIM 768
#define SDIM 512
#define BNUM 32
#define H1DIM 512
#define H2DIM 256
#define GA0 224            // target blocks for apportionment
#define GPAD (GA0 + BNUM)  // 256 launched blocks = 1 block/CU; overflow-proof:
                           // BB[BNUM] = sum(ceil) <= GA0 + BNUM = GPAD always.

typedef float f32x4 __attribute__((ext_vector_type(4)));  // native vec for nt-load

// Deterministic apportionment: n_b = ceil(len_b * GA0 / T), BB = prefix(n_b).
// Computed identically (integer math) in kA and kStats.

// ---------------- Kernel A: block g handles a contiguous s-range of batch b;
// 768 thr = 4 s-subgroups of 192 (256 long ~1.5MB contiguous streams);
// subgroups tree-combined in LDS (fixed order), slot g written. nt x-loads.
__global__ __launch_bounds__(768) void kA_partials(
    const float* __restrict__ x, const int* __restrict__ lengths,
    const float* __restrict__ lw, float* __restrict__ partial) {
  __shared__ int lenS[BNUM];
  __shared__ int BB[BNUM + 1];
  __shared__ float wS[LNUM];
  __shared__ float comb[3][2 * FDIM];  // subgroups 1..3: sum[768] | sq[768]
  const int tid = threadIdx.x;
  const int h  = tid / 192;            // s-subgroup 0..3
  const int tl = tid % 192;            // covers f = 4*tl .. 4*tl+3

  if (tid < BNUM) lenS[tid] = lengths[tid];
  __syncthreads();
  if (tid == 0) {
    int T = 0;
    #pragma unroll
    for (int b = 0; b < BNUM; ++b) T += lenS[b];
    int acc = 0; BB[0] = 0;
    #pragma unroll
    for (int b = 0; b < BNUM; ++b) {
      int nb = (T > 0 && lenS[b] > 0) ? (lenS[b] * GA0 + T - 1) / T : 0;
      acc += nb; BB[b + 1] = acc;
    }
    float m = lw[0];
    #pragma unroll
    for (int l = 1; l < LNUM; ++l) m = fmaxf(m, lw[l]);
    float e[LNUM]; float s = 0.f;
    #pragma unroll
    for (int l = 0; l < LNUM; ++l) { e[l] = expf(lw[l] - m); s += e[l]; }
    #pragma unroll
    for (int l = 0; l < LNUM; ++l) wS[l] = e[l] / s;
  }
  __syncthreads();

  const int g = blockIdx.x;
  if (g >= BB[BNUM]) return;           // idle block; its slot is never read

  int lo = 0, hi = BNUM;
  while (hi - lo > 1) { int mid = (lo + hi) >> 1; if (g >= BB[mid]) lo = mid; else hi = mid; }
  const int b   = lo;
  const int i   = g - BB[b];
  const int n   = BB[b + 1] - BB[b];
  const int len = lenS[b];
  const int base = len / n, rem = len % n;
  const int s0 = i * base + min(i, rem);
  const int cnt = base + (i < rem ? 1 : 0);

  float4 sum = make_float4(0.f, 0.f, 0.f, 0.f);
  float4 sq  = make_float4(0.f, 0.f, 0.f, 0.f);
  const float* xb = x + (size_t)b * SDIM * (LNUM * FDIM) + (size_t)tl * 4;

  for (int s = s0 + h; s < s0 + cnt; s += 4) {
    const float* xs = xb + (size_t)s * (LNUM * FDIM);
    float4 word = make_float4(0.f, 0.f, 0.f, 0.f);
    #pragma unroll
    for (int l = 0; l < LNUM; ++l) {
      f32x4 v = __builtin_nontemporal_load(
          reinterpret_cast<const f32x4*>(xs + l * FDIM));
      const float wl = wS[l];
      word.x = fmaf(wl, v.x, word.x);
      word.y = fmaf(wl, v.y, word.y);
      word.z = fmaf(wl, v.z, word.z);
      word.w = fmaf(wl, v.w, word.w);
    }
    sum.x += word.x; sum.y += word.y; sum.z += word.z; sum.w += word.w;
    sq.x = fmaf(word.x, word.x, sq.x);
    sq.y = fmaf(word.y, word.y, sq.y);
    sq.z = fmaf(word.z, word.z, sq.z);
    sq.w = fmaf(word.w, word.w, sq.w);
  }

  // combine subgroups (fixed order: h0 + h1 + h2 + h3) and write slot g
  if (h > 0) {
    *reinterpret_cast<float4*>(&comb[h - 1][4 * tl]) = sum;
    *reinterpret_cast<float4*>(&comb[h - 1][FDIM + 4 * tl]) = sq;
  }
  __syncthreads();
  if (h == 0) {
    #pragma unroll
    for (int hh = 0; hh < 3; ++hh) {
      float4 s1 = *reinterpret_cast<const float4*>(&comb[hh][4 * tl]);
      float4 q1 = *reinterpret_cast<const float4*>(&comb[hh][FDIM + 4 * tl]);
      sum.x += s1.x; sum.y += s1.y; sum.z += s1.z; sum.w += s1.w;
      sq.x  += q1.x; sq.y  += q1.y; sq.z  += q1.z; sq.w  += q1.w;
    }
    float* p = partial + (size_t)g * (2 * FDIM) + (size_t)tl * 4;
    *reinterpret_cast<float4*>(p) = sum;        // zeros if cnt==0 (slot is read)
    *reinterpret_cast<float4*>(p + FDIM) = sq;
  }
}

// ---------------- Kernel S: reduce slots [BB[b], BB[b+1]) -> feats [B, 2F]
__global__ __launch_bounds__(256) void kStats(
    const float* __restrict__ partial, const int* __restrict__ lengths,
    float* __restrict__ feats) {
  const int b  = blockIdx.x / 12;
  const int cg = blockIdx.x % 12;
  const int cl = threadIdx.x & 63;
  const int k  = threadIdx.x >> 6;      // 0..3
  const int f  = cg * 64 + cl;

  __shared__ int lenS[BNUM];
  __shared__ int BB[BNUM + 1];
  if (threadIdx.x < BNUM) lenS[threadIdx.x] = lengths[threadIdx.x];
  __syncthreads();
  if (threadIdx.x == 0) {
    int T = 0;
    #pragma unroll
    for (int bb = 0; bb < BNUM; ++bb) T += lenS[bb];
    int acc = 0; BB[0] = 0;
    #pragma unroll
    for (int bb = 0; bb < BNUM; ++bb) {
      int nb = (T > 0 && lenS[bb] > 0) ? (lenS[bb] * GA0 + T - 1) / T : 0;
      acc += nb; BB[bb + 1] = acc;
    }
  }
  __syncthreads();

  const int cBeg = BB[b], cEnd = BB[b + 1];
  float ms = 0.f, mq = 0.f;
  for (int cc = cBeg + k; cc < cEnd; cc += 4) {
    const float* p = partial + (size_t)cc * (2 * FDIM);
    ms += p[f];
    mq += p[FDIM + f];
  }
  __shared__ float rs[4][64], rq[4][64];
  rs[k][cl] = ms; rq[k][cl] = mq;
  __syncthreads();

  if (threadIdx.x < 64) {
    ms = rs[0][cl] + rs[1][cl] + rs[2][cl] + rs[3][cl];
    mq = rq[0][cl] + rq[1][cl] + rq[2][cl] + rq[3][cl];
    const int n = lenS[b];
    const float fn = (float)n;
    const float mean = ms / fmaxf(fn, 1.f);
    const float var = (mq - fn * mean * mean) / fmaxf(fn - 1.f, 1.f);
    const float sd = (n > 1) ? sqrtf(fmaxf(var, 0.f)) : 0.f;
    feats[(size_t)b * 2 * FDIM + f] = mean;
    feats[(size_t)b * 2 * FDIM + FDIM + f] = sd;
  }
}

// ---------------- Kernel C (R15-identical): batch-blocked FC1
__global__ __launch_bounds__(512) void kFC1b(
    const float* __restrict__ feats, const float* __restrict__ W1,
    const float* __restrict__ b1, float* __restrict__ h1) {
  const int bg = blockIdx.x >> 4;      // 0..7 (4 consecutive b's)
  const int jt = blockIdx.x & 15;      // 0..15 (32 cols each)
  const int t  = threadIdx.x;
  const int jl = t & 31;
  const int kh = t >> 5;               // 0..15 (96 k's each)
  const int j  = jt * 32 + jl;

  __shared__ float fs[4][2 * FDIM];    // 24 KB
  __shared__ float red[16][4][32];     // 8 KB

  for (int i = t; i < 4 * 2 * FDIM; i += 512) {
    const int bb = i / (2 * FDIM), ff = i % (2 * FDIM);
    fs[bb][ff] = feats[(size_t)(bg * 4 + bb) * 2 * FDIM + ff];
  }
  __syncthreads();

  float a0 = 0.f, a1 = 0.f, a2 = 0.f, a3 = 0.f;
  const float* wp = W1 + (size_t)kh * 96 * H1DIM + j;
  const int k0 = kh * 96;
  #pragma unroll 8
  for (int i = 0; i < 96; ++i) {
    const float w = wp[(size_t)i * H1DIM];
    a0 = fmaf(fs[0][k0 + i], w, a0);
    a1 = fmaf(fs[1][k0 + i], w, a1);
    a2 = fmaf(fs[2][k0 + i], w, a2);
    a3 = fmaf(fs[3][k0 + i], w, a3);
  }
  red[kh][0][jl] = a0;
  red[kh][1][jl] = a1;
  red[kh][2][jl] = a2;
  red[kh][3][jl] = a3;
  __syncthreads();

  if (t < 128) {
    const int bb = t >> 5, jj = t & 31;
    float a = b1[jt * 32 + jj];
    #pragma unroll
    for (int kk = 0; kk < 16; ++kk) a += red[kk][bb][jj];
    h1[(size_t)(bg * 4 + bb) * H1DIM + jt * 32 + jj] = fmaxf(a, 0.f);
  }
}

// ---------------- Kernel D (R15-identical): h2 = relu(h1 @ W2 + b2); out = h2 @ W3 + b3
__global__ __launch_bounds__(512) void kFC23(
    const float* __restrict__ h1, const float* __restrict__ W2,
    const float* __restrict__ b2, const float* __restrict__ W3,
    const float* __restrict__ b3, float* __restrict__ out) {
  const int b = blockIdx.x;
  const int t = threadIdx.x;
  const int jl = t & 255;
  const int kh = t >> 8;              // 0..1

  __shared__ float hs[H1DIM];         // 2 KB
  __shared__ float red[2 * H2DIM];    // 2 KB
  __shared__ float wred[8];

  if (t < H1DIM) hs[t] = h1[(size_t)b * H1DIM + t];
  __syncthreads();

  const float* wcol = W2 + (size_t)kh * 256 * H2DIM + jl;
  const float* hk = hs + kh * 256;
  float acc = 0.f;
  #pragma unroll 16
  for (int i = 0; i < 256; ++i)
    acc = fmaf(hk[i], wcol[(size_t)i * H2DIM], acc);
  red[kh * H2DIM + jl] = acc;
  __syncthreads();

  float v = 0.f;
  if (t < H2DIM) {
    const float h2 = fmaxf(red[t] + red[H2DIM + t] + b2[t], 0.f);
    v = h2 * W3[t];
  }
  #pragma unroll
  for (int off = 32; off > 0; off >>= 1) v += __shfl_down(v, off, 64);
  if ((t & 63) == 0) wred[t >> 6] = v;
  __syncthreads();
  if (t == 0) {
    float r = b3[0];
    #pragma unroll
    for (int i = 0; i < 8; ++i) r += wred[i];
    out[b] = r;
  }
}

extern "C" void kernel_launch(void* const* d_in, const int* in_sizes, int n_in,
                              void* d_out, int out_size, void* d_ws, size_t ws_size,
                              hipStream_t stream) {
  const float* x       = (const float*)d_in[0];
  const int*   lengths = (const int*)  d_in[1];
  const float* lw      = (const float*)d_in[2];
  const float* W1      = (const float*)d_in[3];
  const float* b1      = (const float*)d_in[4];
  const float* W2      = (const float*)d_in[5];
  const float* b2      = (const float*)d_in[6];
  const float* W3      = (const float*)d_in[7];
  const float* b3      = (const float*)d_in[8];
  float* out = (float*)d_out;

  float* partial = (float*)d_ws;                              // GPAD * 2F floats (1.6 MB)
  float* feats   = partial + (size_t)GPAD * 2 * FDIM;         // B * 2F
  float* h1      = feats + (size_t)BNUM * 2 * FDIM;           // B * H1

  kA_partials<<<dim3(GPAD), dim3(768), 0, stream>>>(x, lengths, lw, partial);
  kStats<<<dim3(BNUM * 12), dim3(256), 0, stream>>>(partial, lengths, feats);
  kFC1b<<<dim3(128), dim3(512), 0, stream>>>(feats, W1, b1, h1);
  kFC23<<<dim3(BNUM), dim3(512), 0, stream>>>(h1, W2, b2, W3, b3, out);
}